// Round 4
// baseline (105.350 us; speedup 1.0000x reference)
//
#include <hip/hip_runtime.h>
#include <math.h>

#define Bc 8
#define Sc 512
#define Hc 768
#define Ec 16
#define Mc 4
#define Cc 96
#define Pc 240   // E*E - E

// ws layout (floats):
//   att_rows : B*E*S   = 65536
//   cnt      : B*E     = 128
//   docv     : B*E*H   = 98304
//   ctxu     : B*E*H   = 98304   (atomic-accumulated, zeroed each launch)
//   total ≈ 1.05 MB

// ---------------------------------------------------------------------------
// K1: per (b,e) — mask compaction, count, att_rows (sum of masked attention
// rows), doc (online logsumexp of masked embedding rows).
// ---------------------------------------------------------------------------
__global__ __launch_bounds__(256) void k_mask_att_doc(
    const float* __restrict__ emb, const float* __restrict__ att,
    const int* __restrict__ starts, const int* __restrict__ lens,
    float* __restrict__ att_rows, float* __restrict__ cnt,
    float* __restrict__ docv)
{
  int be = blockIdx.x;            // b*16 + e
  int b  = be >> 4;
  int tid = threadIdx.x;

  __shared__ int slist[32];       // max 4 mentions * len<=5 = 20 positions
  __shared__ int n_sh;
  if (tid == 0) n_sh = 0;
  __syncthreads();

  int base = be * Mc;
  int st0 = starts[base+0], st1 = starts[base+1];
  int st2 = starts[base+2], st3 = starts[base+3];
  int en0 = st0 + lens[base+0], en1 = st1 + lens[base+1];
  int en2 = st2 + lens[base+2], en3 = st3 + lens[base+3];

  // mask[s] = any_m (s >= start+1 && s <= start+len)  — compact into slist
  for (int s = tid; s < Sc; s += 256) {
    bool in = (s > st0 && s <= en0) || (s > st1 && s <= en1) ||
              (s > st2 && s <= en2) || (s > st3 && s <= en3);
    if (in) { int pos = atomicAdd(&n_sh, 1); slist[pos] = s; }
  }
  __syncthreads();
  int n = n_sh;                   // guaranteed >= 1

  // att_rows[be][t] = sum over masked s of attention[b][s][t]
  float a0 = 0.f, a1 = 0.f;
  for (int i = 0; i < n; ++i) {
    const float* row = att + ((size_t)b * Sc + slist[i]) * Sc;
    a0 += row[tid];
    a1 += row[tid + 256];
  }
  float* arow = att_rows + (size_t)be * Sc;
  arow[tid]       = a0;
  arow[tid + 256] = a1;
  if (tid == 0) cnt[be] = (float)n;

  // doc[be][h] = logsumexp over masked s of emb[b][s][h]  (online, n>=1)
  #pragma unroll
  for (int kk = 0; kk < 3; ++kk) {
    int h = tid + kk * 256;
    const float* ecol = emb + (size_t)b * Sc * Hc + h;
    float m = ecol[(size_t)slist[0] * Hc];
    float l = 1.0f;
    for (int i = 1; i < n; ++i) {
      float v  = ecol[(size_t)slist[i] * Hc];
      float nm = fmaxf(m, v);
      l = l * __expf(m - nm) + __expf(v - nm);
      m = nm;
    }
    docv[(size_t)be * Hc + h] = m + __logf(l);
  }
}

// ---------------------------------------------------------------------------
// K2: ctxu[b,e,h] += sum over t-chunk of att_rows[b,e,t] * emb[b,t,h]
// grid (tchunk=4, hchunk=3, b=8); 16 e-accumulators per thread.
// emb is read exactly once across the whole grid.
// ---------------------------------------------------------------------------
__global__ __launch_bounds__(256) void k_context(
    const float* __restrict__ emb, const float* __restrict__ att_rows,
    float* __restrict__ ctxu)
{
  int tchunk = blockIdx.x;        // 0..3  (128 t each)
  int hchunk = blockIdx.y;        // 0..2  (256 h each)
  int b      = blockIdx.z;
  int tid = threadIdx.x;
  int h  = hchunk * 256 + tid;
  int t0 = tchunk * 128;

  __shared__ float ar[128][16];   // [tt][e] — uniform-address broadcast reads
  for (int idx = tid; idx < 128 * 16; idx += 256) {
    int e = idx & 15, tt = idx >> 4;
    ar[tt][e] = att_rows[((size_t)(b * Ec + e)) * Sc + t0 + tt];
  }
  __syncthreads();

  float acc[16];
  #pragma unroll
  for (int e = 0; e < 16; ++e) acc[e] = 0.f;

  const float* ecol = emb + ((size_t)b * Sc + t0) * Hc + h;
  for (int tt = 0; tt < 128; ++tt) {
    float ev = ecol[(size_t)tt * Hc];
    #pragma unroll
    for (int e = 0; e < 16; ++e) acc[e] = fmaf(ar[tt][e], ev, acc[e]);
  }

  float* outb = ctxu + (size_t)(b * Ec) * Hc + h;
  #pragma unroll
  for (int e = 0; e < 16; ++e) atomicAdd(outb + (size_t)e * Hc, acc[e]);
}

// ---------------------------------------------------------------------------
// K3: assemble output. Row r = b*240 + p; pair (i,j) from ~eye(16) row-major.
// out[r][0][h]=cls, [1]=doc[i], [2]=doc[j], [3]=ctx[i]*ctx[j] (normalized).
// Then labels appended as float.
// ---------------------------------------------------------------------------
__global__ __launch_bounds__(256) void k_assemble(
    const float* __restrict__ emb, const int* __restrict__ labels,
    const float* __restrict__ docv, const float* __restrict__ ctxu,
    const float* __restrict__ cnt, float* __restrict__ out)
{
  int r = blockIdx.x;
  int b = r / Pc, p = r % Pc;
  int i = p / 15, k = p % 15;
  int j = k + (k >= i ? 1 : 0);
  int tid = threadIdx.x;

  float ci = 1.0f / cnt[b * Ec + i];
  float cj = 1.0f / cnt[b * Ec + j];

  size_t rowbase = (size_t)r * 4 * Hc;
  const float* clsrow = emb  + (size_t)b * Sc * Hc;          // s = 0
  const float* di_ = docv + (size_t)(b * Ec + i) * Hc;
  const float* dj_ = docv + (size_t)(b * Ec + j) * Hc;
  const float* xi_ = ctxu + (size_t)(b * Ec + i) * Hc;
  const float* xj_ = ctxu + (size_t)(b * Ec + j) * Hc;

  #pragma unroll
  for (int kk = 0; kk < 3; ++kk) {
    int h = tid + kk * 256;
    out[rowbase +           h] = clsrow[h];
    out[rowbase +     Hc  + h] = di_[h];
    out[rowbase + 2 * Hc  + h] = dj_[h];
    out[rowbase + 3 * Hc  + h] = (xi_[h] * ci) * (xj_[h] * cj);
  }

  if (tid < Cc) {
    const int* lrow = labels + (((size_t)b * Ec + i) * Ec + j) * Cc;
    out[(size_t)Bc * Pc * 4 * Hc + (size_t)r * Cc + tid] = (float)lrow[tid];
  }
}

extern "C" void kernel_launch(void* const* d_in, const int* in_sizes, int n_in,
                              void* d_out, int out_size, void* d_ws, size_t ws_size,
                              hipStream_t stream) {
  const float* emb    = (const float*)d_in[0];
  const float* att    = (const float*)d_in[1];
  const int*   starts = (const int*)d_in[2];
  const int*   lens   = (const int*)d_in[3];
  const int*   labels = (const int*)d_in[4];
  float* out = (float*)d_out;

  float* att_rows = (float*)d_ws;
  float* cnt      = att_rows + (size_t)Bc * Ec * Sc;
  float* docv     = cnt      + (size_t)Bc * Ec;
  float* ctxu     = docv     + (size_t)Bc * Ec * Hc;

  hipMemsetAsync(ctxu, 0, (size_t)Bc * Ec * Hc * sizeof(float), stream);

  k_mask_att_doc<<<Bc * Ec, 256, 0, stream>>>(emb, att, starts, lens,
                                              att_rows, cnt, docv);
  k_context<<<dim3(4, 3, Bc), 256, 0, stream>>>(emb, att_rows, ctxu);
  k_assemble<<<Bc * Pc, 256, 0, stream>>>(emb, labels, docv, ctxu, cnt, out);
}

// Round 5
// 98.863 us; speedup vs baseline: 1.0656x; 1.0656x over previous
//
#include <hip/hip_runtime.h>
#include <math.h>

#define Bc 8
#define Sc 512
#define Hc 768
#define Ec 16
#define Mc 4
#define Cc 96
#define Pc 240   // E*E - E

// ws layout (floats):
//   att_rows : B*E*S   = 65536
//   cnt      : B*E     = 128
//   docv     : B*E*H   = 98304
//   ctxu     : B*E*H   = 98304   (atomic-accumulated; zeroed by K1)

// ---------------------------------------------------------------------------
// K1: per (b,e) — mask compaction, count, att_rows (sum of masked attention
// rows), doc (online logsumexp of masked embedding rows), zero ctxu slice.
// ---------------------------------------------------------------------------
__global__ __launch_bounds__(256) void k_mask_att_doc(
    const float* __restrict__ emb, const float* __restrict__ att,
    const int* __restrict__ starts, const int* __restrict__ lens,
    float* __restrict__ att_rows, float* __restrict__ cnt,
    float* __restrict__ docv, float* __restrict__ ctxu)
{
  int be = blockIdx.x;            // b*16 + e
  int b  = be >> 4;
  int tid = threadIdx.x;

  // zero this (b,e)'s ctxu slice (K2 atomically accumulates into it)
  {
    float* z = ctxu + (size_t)be * Hc;
    z[tid] = 0.f; z[tid + 256] = 0.f; z[tid + 512] = 0.f;
  }

  __shared__ int slist[32];       // max 4 mentions * len<=5 = 20 positions
  __shared__ int n_sh;
  if (tid == 0) n_sh = 0;
  __syncthreads();

  int base = be * Mc;
  int st0 = starts[base+0], st1 = starts[base+1];
  int st2 = starts[base+2], st3 = starts[base+3];
  int en0 = st0 + lens[base+0], en1 = st1 + lens[base+1];
  int en2 = st2 + lens[base+2], en3 = st3 + lens[base+3];

  // mask[s] = any_m (s >= start+1 && s <= start+len)  — compact into slist
  for (int s = tid; s < Sc; s += 256) {
    bool in = (s > st0 && s <= en0) || (s > st1 && s <= en1) ||
              (s > st2 && s <= en2) || (s > st3 && s <= en3);
    if (in) { int pos = atomicAdd(&n_sh, 1); slist[pos] = s; }
  }
  __syncthreads();
  int n = n_sh;                   // guaranteed >= 1

  // att_rows[be][t] = sum over masked s of attention[b][s][t]  (float2)
  float2 a = make_float2(0.f, 0.f);
  for (int i = 0; i < n; ++i) {
    const float2* row2 =
        (const float2*)(att + ((size_t)b * Sc + slist[i]) * Sc);
    float2 v = row2[tid];
    a.x += v.x; a.y += v.y;
  }
  ((float2*)(att_rows + (size_t)be * Sc))[tid] = a;
  if (tid == 0) cnt[be] = (float)n;

  // doc[be][h] = logsumexp over masked s of emb[b][s][h]  (online, n>=1)
  #pragma unroll
  for (int kk = 0; kk < 3; ++kk) {
    int h = tid + kk * 256;
    const float* ecol = emb + (size_t)b * Sc * Hc + h;
    float m = ecol[(size_t)slist[0] * Hc];
    float l = 1.0f;
    for (int i = 1; i < n; ++i) {
      float v  = ecol[(size_t)slist[i] * Hc];
      float nm = fmaxf(m, v);
      l = l * __expf(m - nm) + __expf(v - nm);
      m = nm;
    }
    docv[(size_t)be * Hc + h] = m + __logf(l);
  }
}

// ---------------------------------------------------------------------------
// K2: ctxu[b,e,h] += sum over 64-t-chunk of att_rows[b,e,t] * emb[b,t,h]
// grid (tchunk=8, hchunk=3, b=8) = 192 blocks; 16 e-accumulators per thread.
// emb is read exactly once across the whole grid.
// LDS ar[64][20]: 80B row stride -> 16B-aligned float4 broadcast reads,
// and staging writes spread over 8 banks instead of 2.
// ---------------------------------------------------------------------------
__global__ __launch_bounds__(256) void k_context(
    const float* __restrict__ emb, const float* __restrict__ att_rows,
    float* __restrict__ ctxu)
{
  int tchunk = blockIdx.x;        // 0..7  (64 t each)
  int hchunk = blockIdx.y;        // 0..2  (256 h each)
  int b      = blockIdx.z;
  int tid = threadIdx.x;
  int h  = hchunk * 256 + tid;
  int t0 = tchunk * 64;

  __shared__ float ar[64][20];
  {
    int e = tid >> 4, q = tid & 15;   // 16 e * 16 float4 = 256 threads
    const float4* src =
        (const float4*)(att_rows + ((size_t)(b * Ec + e)) * Sc + t0);
    float4 v = src[q];
    ar[q*4+0][e] = v.x;
    ar[q*4+1][e] = v.y;
    ar[q*4+2][e] = v.z;
    ar[q*4+3][e] = v.w;
  }
  __syncthreads();

  float acc[16];
  #pragma unroll
  for (int e = 0; e < 16; ++e) acc[e] = 0.f;

  const float* ecol = emb + ((size_t)b * Sc + t0) * Hc + h;
  #pragma unroll 4
  for (int tt = 0; tt < 64; ++tt) {
    float ev = ecol[(size_t)tt * Hc];
    const float4* arv = (const float4*)&ar[tt][0];  // 16B-aligned broadcast
    float4 a0 = arv[0], a1 = arv[1], a2 = arv[2], a3 = arv[3];
    acc[ 0] = fmaf(a0.x, ev, acc[ 0]);
    acc[ 1] = fmaf(a0.y, ev, acc[ 1]);
    acc[ 2] = fmaf(a0.z, ev, acc[ 2]);
    acc[ 3] = fmaf(a0.w, ev, acc[ 3]);
    acc[ 4] = fmaf(a1.x, ev, acc[ 4]);
    acc[ 5] = fmaf(a1.y, ev, acc[ 5]);
    acc[ 6] = fmaf(a1.z, ev, acc[ 6]);
    acc[ 7] = fmaf(a1.w, ev, acc[ 7]);
    acc[ 8] = fmaf(a2.x, ev, acc[ 8]);
    acc[ 9] = fmaf(a2.y, ev, acc[ 9]);
    acc[10] = fmaf(a2.z, ev, acc[10]);
    acc[11] = fmaf(a2.w, ev, acc[11]);
    acc[12] = fmaf(a3.x, ev, acc[12]);
    acc[13] = fmaf(a3.y, ev, acc[13]);
    acc[14] = fmaf(a3.z, ev, acc[14]);
    acc[15] = fmaf(a3.w, ev, acc[15]);
  }

  float* outb = ctxu + (size_t)(b * Ec) * Hc + h;
  #pragma unroll
  for (int e = 0; e < 16; ++e) atomicAdd(outb + (size_t)e * Hc, acc[e]);
}

// ---------------------------------------------------------------------------
// K3: assemble output, all float4. Row r = b*240 + p; (i,j) from ~eye(16)
// row-major. out[r][0]=cls, [1]=doc[i], [2]=doc[j], [3]=ctx[i]*ctx[j].
// 192 threads = 768/4 float4 per section. Labels as float via int4.
// ---------------------------------------------------------------------------
__global__ __launch_bounds__(192) void k_assemble(
    const float* __restrict__ emb, const int* __restrict__ labels,
    const float* __restrict__ docv, const float* __restrict__ ctxu,
    const float* __restrict__ cnt, float* __restrict__ out)
{
  int r = blockIdx.x;
  int b = r / Pc, p = r % Pc;
  int i = p / 15, k = p % 15;
  int j = k + (k >= i ? 1 : 0);
  int tid = threadIdx.x;

  float ci = 1.0f / cnt[b * Ec + i];
  float cj = 1.0f / cnt[b * Ec + j];

  const float4* cls4 = (const float4*)(emb  + (size_t)b * Sc * Hc);  // s=0
  const float4* di4  = (const float4*)(docv + (size_t)(b * Ec + i) * Hc);
  const float4* dj4  = (const float4*)(docv + (size_t)(b * Ec + j) * Hc);
  const float4* xi4  = (const float4*)(ctxu + (size_t)(b * Ec + i) * Hc);
  const float4* xj4  = (const float4*)(ctxu + (size_t)(b * Ec + j) * Hc);
  float4* o = (float4*)(out + (size_t)r * 4 * Hc);

  o[      tid] = cls4[tid];
  o[192 + tid] = di4[tid];
  o[384 + tid] = dj4[tid];
  float4 xa = xi4[tid], xb = xj4[tid], c;
  c.x = (xa.x * ci) * (xb.x * cj);
  c.y = (xa.y * ci) * (xb.y * cj);
  c.z = (xa.z * ci) * (xb.z * cj);
  c.w = (xa.w * ci) * (xb.w * cj);
  o[576 + tid] = c;

  if (tid < 24) {
    const int4* l4 =
        (const int4*)(labels + (((size_t)b * Ec + i) * Ec + j) * Cc);
    int4 v = l4[tid];
    float4 f;
    f.x = (float)v.x; f.y = (float)v.y; f.z = (float)v.z; f.w = (float)v.w;
    ((float4*)(out + (size_t)Bc * Pc * 4 * Hc + (size_t)r * Cc))[tid] = f;
  }
}

extern "C" void kernel_launch(void* const* d_in, const int* in_sizes, int n_in,
                              void* d_out, int out_size, void* d_ws, size_t ws_size,
                              hipStream_t stream) {
  const float* emb    = (const float*)d_in[0];
  const float* att    = (const float*)d_in[1];
  const int*   starts = (const int*)d_in[2];
  const int*   lens   = (const int*)d_in[3];
  const int*   labels = (const int*)d_in[4];
  float* out = (float*)d_out;

  float* att_rows = (float*)d_ws;
  float* cnt      = att_rows + (size_t)Bc * Ec * Sc;
  float* docv     = cnt      + (size_t)Bc * Ec;
  float* ctxu     = docv     + (size_t)Bc * Ec * Hc;

  k_mask_att_doc<<<Bc * Ec, 256, 0, stream>>>(emb, att, starts, lens,
                                              att_rows, cnt, docv, ctxu);
  k_context<<<dim3(8, 3, Bc), 256, 0, stream>>>(emb, att_rows, ctxu);
  k_assemble<<<Bc * Pc, 192, 0, stream>>>(emb, labels, docv, ctxu, cnt, out);
}